// Round 1
// baseline (54937.469 us; speedup 1.0000x reference)
//
#include <hip/hip_runtime.h>
#include <cstddef>
#include <math.h>

// ---------------- model dims ----------------
#define BB 16
#define HIST 336
#define PRED 48
#define SS 384
#define HH 768
#define NL 12
#define FF_ 3072
#define DIN 481
#define NE_ 8
#define VV 40000

// ---------------- GEMM: C[N,M] = op(A[N,K] @ W[K,M] + bias[M]) ----------------
// OP 0: none  (write)
// OP 1: gelu  (write)
// OP 2: C += gelu(v) * scale[row*ss]   (accumulate; scale pre-offset to expert col)
#define BM 64
#define BN 64
#define BKK 16

template<int OP>
__global__ __launch_bounds__(256)
void gemm_f32(const float* __restrict__ A, const float* __restrict__ W,
              const float* __restrict__ bias, float* __restrict__ C,
              int N, int K, int M,
              const float* __restrict__ scale, int ss)
{
    __shared__ float As[BKK][BM + 4];   // transposed A tile, padded (stride 68 floats, 16B-aligned)
    __shared__ float Ws[BKK][BN];
    const int tid = threadIdx.x;
    const int tx = tid & 15, ty = tid >> 4;
    const int rowBase = blockIdx.y * BM;
    const int colBase = blockIdx.x * BN;
    float acc[4][4] = {};
    const int nk = (K + BKK - 1) / BKK;
    for (int kt = 0; kt < nk; ++kt) {
        const int k0 = kt * BKK;
        // load A tile: 64 rows x 16 k
        #pragma unroll
        for (int j = 0; j < 4; ++j) {
            int r = (tid >> 4) + j * 16;
            int c = tid & 15;
            int gr = rowBase + r, gc = k0 + c;
            As[c][r] = (gr < N && gc < K) ? A[(size_t)gr * K + gc] : 0.f;
        }
        // load W tile: 16 k x 64 cols
        #pragma unroll
        for (int j = 0; j < 4; ++j) {
            int r = (tid >> 6) + j * 4;
            int c = tid & 63;
            int gr = k0 + r, gc = colBase + c;
            Ws[r][c] = (gr < K && gc < M) ? W[(size_t)gr * M + gc] : 0.f;
        }
        __syncthreads();
        #pragma unroll
        for (int k = 0; k < BKK; ++k) {
            float4 a4 = *reinterpret_cast<const float4*>(&As[k][ty << 2]);
            float4 b4 = *reinterpret_cast<const float4*>(&Ws[k][tx << 2]);
            float a[4] = {a4.x, a4.y, a4.z, a4.w};
            float b[4] = {b4.x, b4.y, b4.z, b4.w};
            #pragma unroll
            for (int i = 0; i < 4; ++i)
                #pragma unroll
                for (int j = 0; j < 4; ++j)
                    acc[i][j] = fmaf(a[i], b[j], acc[i][j]);
        }
        __syncthreads();
    }
    #pragma unroll
    for (int i = 0; i < 4; ++i) {
        int row = rowBase + (ty << 2) + i;
        if (row >= N) continue;
        float sc = (OP == 2) ? scale[(size_t)row * ss] : 1.f;
        #pragma unroll
        for (int j = 0; j < 4; ++j) {
            int col = colBase + (tx << 2) + j;
            if (col >= M) continue;
            float v = acc[i][j] + bias[col];
            if (OP >= 1) v = 0.5f * v * (1.f + erff(v * 0.70710678118654752f));
            if (OP == 2) C[(size_t)row * M + col] += v * sc;
            else         C[(size_t)row * M + col] = v;
        }
    }
}

// ---------------- feature gather + concat + LayerNorm(481) ----------------
__global__ __launch_bounds__(512)
void build_x(const int* __restrict__ isf, const int* __restrict__ hloc,
             const int* __restrict__ psf,
             const float* __restrict__ dayE, const float* __restrict__ timeE,
             const float* __restrict__ dowE, const float* __restrict__ wdE,
             const float* __restrict__ locE,
             const float* __restrict__ g, const float* __restrict__ b2,
             float* __restrict__ x)
{
    const int tok = blockIdx.x;            // 0..6143
    const int b = tok / SS, s = tok % SS;
    const int tid = threadIdx.x;
    __shared__ float red[512];
    const int* f;
    int loc = -1;
    if (s < HIST) { f = isf + (b * HIST + s) * 6; loc = hloc[b * HIST + s]; }
    else          { f = psf + (b * PRED + (s - HIST)) * 6; }
    float val = 0.f;
    if (tid < DIN) {
        int c = tid;
        if      (c < 64)  val = dayE[f[0] * 64 + c];
        else if (c < 128) val = timeE[f[1] * 64 + (c - 64)];
        else if (c < 192) val = dowE[f[3] * 64 + (c - 128)];
        else if (c < 224) val = wdE[f[4] * 32 + (c - 192)];
        else if (c == 224) val = (float)f[5];
        else val = (loc >= 0) ? locE[(size_t)loc * 256 + (c - 225)] : 0.f;
    }
    red[tid] = (tid < DIN) ? val : 0.f;
    __syncthreads();
    for (int o = 256; o > 0; o >>= 1) { if (tid < o) red[tid] += red[tid + o]; __syncthreads(); }
    float mean = red[0] / (float)DIN;
    __syncthreads();
    float d = (tid < DIN) ? (val - mean) : 0.f;
    red[tid] = d * d;
    __syncthreads();
    for (int o = 256; o > 0; o >>= 1) { if (tid < o) red[tid] += red[tid + o]; __syncthreads(); }
    float rstd = rsqrtf(red[0] / (float)DIN + 1e-5f);
    if (tid < DIN) x[(size_t)tok * DIN + tid] = (val - mean) * rstd * g[tid] + b2[tid];
}

// ---------------- LayerNorm over 768, fused residual / pos+tt add ----------------
__global__ __launch_bounds__(256)
void ln768(float* __restrict__ out, const float* __restrict__ in1,
           const float* __restrict__ in2, const float* __restrict__ pos,
           const float* __restrict__ tt,
           const float* __restrict__ g, const float* __restrict__ b2,
           float eps)
{
    const int D = HH;
    const int row = blockIdx.x;
    const int s = row % SS;
    __shared__ float buf[HH];
    __shared__ float red[256];
    const int tid = threadIdx.x;
    float partial = 0.f;
    #pragma unroll
    for (int i = 0; i < 3; ++i) {
        int c = tid + i * 256;
        float v = in1[(size_t)row * D + c];
        if (in2) v += in2[(size_t)row * D + c];
        if (pos) v += pos[(size_t)s * D + c];
        if (tt)  v += tt[c];
        buf[c] = v;
        partial += v;
    }
    red[tid] = partial; __syncthreads();
    for (int o = 128; o > 0; o >>= 1) { if (tid < o) red[tid] += red[tid + o]; __syncthreads(); }
    float mean = red[0] / (float)D;
    __syncthreads();
    float p2 = 0.f;
    #pragma unroll
    for (int i = 0; i < 3; ++i) { float d = buf[tid + i * 256] - mean; p2 += d * d; }
    red[tid] = p2; __syncthreads();
    for (int o = 128; o > 0; o >>= 1) { if (tid < o) red[tid] += red[tid + o]; __syncthreads(); }
    float rstd = rsqrtf(red[0] / (float)D + eps);
    #pragma unroll
    for (int i = 0; i < 3; ++i) {
        int c = tid + i * 256;
        out[(size_t)row * D + c] = (buf[c] - mean) * rstd * g[c] + b2[c];
    }
}

// ---------------- fused attention: one block = one (b, head, q-row) ----------------
__global__ __launch_bounds__(128)
void attn_f32(const float* __restrict__ Q, const float* __restrict__ Kp,
              const float* __restrict__ Vp, float* __restrict__ O,
              int nh, int hd, float scale)
{
    int idx = blockIdx.x;
    const int qi = idx % SS; idx /= SS;
    const int h = idx % nh;  idx /= nh;
    const int b = idx;
    const int H_ = nh * hd;
    __shared__ float qs[64];
    __shared__ float sc[SS];
    __shared__ float red[128];
    const int tid = threadIdx.x;
    const float* qrow = Q + ((size_t)(b * SS + qi) * H_ + h * hd);
    if (tid < hd) qs[tid] = qrow[tid];
    __syncthreads();
    for (int j = tid; j < SS; j += 128) {
        const float* krow = Kp + ((size_t)(b * SS + j) * H_ + h * hd);
        float s = 0.f;
        for (int d = 0; d < hd; ++d) s = fmaf(qs[d], krow[d], s);
        sc[j] = s * scale;
    }
    __syncthreads();
    float lmax = -1e30f;
    for (int j = tid; j < SS; j += 128) lmax = fmaxf(lmax, sc[j]);
    red[tid] = lmax; __syncthreads();
    for (int o = 64; o > 0; o >>= 1) { if (tid < o) red[tid] = fmaxf(red[tid], red[tid + o]); __syncthreads(); }
    const float mx = red[0];
    __syncthreads();
    float lsum = 0.f;
    for (int j = tid; j < SS; j += 128) { float e = __expf(sc[j] - mx); sc[j] = e; lsum += e; }
    red[tid] = lsum; __syncthreads();
    for (int o = 64; o > 0; o >>= 1) { if (tid < o) red[tid] += red[tid + o]; __syncthreads(); }
    const float inv = 1.f / red[0];
    __syncthreads();
    if (tid < hd) {
        float o = 0.f;
        for (int j = 0; j < SS; ++j)
            o = fmaf(sc[j], Vp[(size_t)(b * SS + j) * H_ + h * hd + tid], o);
        O[(size_t)(b * SS + qi) * H_ + h * hd + tid] = o * inv;
    }
}

// ---------------- gather future-token rows ----------------
__global__ void gather_fut(const float* __restrict__ src, float* __restrict__ dst, int D)
{
    const int r = blockIdx.x;              // 0..767
    const int b = r / PRED, t = r % PRED;
    const int srow = b * SS + HIST + t;
    for (int c = threadIdx.x; c < D; c += blockDim.x)
        dst[(size_t)r * D + c] = src[(size_t)srow * D + c];
}

// ---------------- gate softmax over 8 experts ----------------
__global__ void gate_softmax(float* __restrict__ gate)
{
    const int r = blockIdx.x * blockDim.x + threadIdx.x;
    if (r >= BB * PRED) return;
    float* p = gate + (size_t)r * NE_;
    float mx = p[0];
    for (int e = 1; e < NE_; ++e) mx = fmaxf(mx, p[e]);
    float s = 0.f, v[NE_];
    for (int e = 0; e < NE_; ++e) { v[e] = __expf(p[e] - mx); s += v[e]; }
    for (int e = 0; e < NE_; ++e) p[e] = v[e] / s;
}

// ---------------- host ----------------
static inline void launch_gemm(const float* A, const float* W, const float* bias, float* C,
                               int N, int K, int M, int op,
                               const float* scale, int ss, hipStream_t stream)
{
    dim3 grid((M + BN - 1) / BN, (N + BM - 1) / BM);
    if (op == 0)      gemm_f32<0><<<grid, 256, 0, stream>>>(A, W, bias, C, N, K, M, scale, ss);
    else if (op == 1) gemm_f32<1><<<grid, 256, 0, stream>>>(A, W, bias, C, N, K, M, scale, ss);
    else              gemm_f32<2><<<grid, 256, 0, stream>>>(A, W, bias, C, N, K, M, scale, ss);
}

extern "C" void kernel_launch(void* const* d_in, const int* in_sizes, int n_in,
                              void* d_out, int out_size, void* d_ws, size_t ws_size,
                              hipStream_t stream)
{
    const int*   isf   = (const int*)  d_in[0];
    const int*   hloc  = (const int*)  d_in[1];
    const int*   psf   = (const int*)  d_in[2];
    const float* dayE  = (const float*)d_in[3];
    const float* timeE = (const float*)d_in[4];
    const float* dowE  = (const float*)d_in[5];
    const float* wdE   = (const float*)d_in[6];
    const float* locE  = (const float*)d_in[7];
    const float* ln_g  = (const float*)d_in[8];
    const float* ln_b  = (const float*)d_in[9];
    const float* inpW  = (const float*)d_in[10];
    const float* inpB  = (const float*)d_in[11];
    const float* resW  = (const float*)d_in[12];
    const float* resB  = (const float*)d_in[13];
    const float* saqW  = (const float*)d_in[14];
    const float* sakW  = (const float*)d_in[15];
    const float* savW  = (const float*)d_in[16];
    const float* saoW  = (const float*)d_in[17];
    const float* saqB  = (const float*)d_in[18];
    const float* sakB  = (const float*)d_in[19];
    const float* savB  = (const float*)d_in[20];
    const float* saoB  = (const float*)d_in[21];
    const float* salnG = (const float*)d_in[22];
    const float* salnB = (const float*)d_in[23];
    const float* posE  = (const float*)d_in[24];
    const float* ttE   = (const float*)d_in[25];
    const float* belnG = (const float*)d_in[26];
    const float* belnB = (const float*)d_in[27];
    const float* bqW   = (const float*)d_in[28];
    const float* bkW   = (const float*)d_in[29];
    const float* bvW   = (const float*)d_in[30];
    const float* boW   = (const float*)d_in[31];
    const float* bqB   = (const float*)d_in[32];
    const float* bkB   = (const float*)d_in[33];
    const float* bvB   = (const float*)d_in[34];
    const float* boB   = (const float*)d_in[35];
    const float* balnG = (const float*)d_in[36];
    const float* balnB = (const float*)d_in[37];
    const float* bf1W  = (const float*)d_in[38];
    const float* bf1B  = (const float*)d_in[39];
    const float* bf2W  = (const float*)d_in[40];
    const float* bf2B  = (const float*)d_in[41];
    const float* bflnG = (const float*)d_in[42];
    const float* bflnB = (const float*)d_in[43];
    const float* moeW  = (const float*)d_in[44];
    const float* moeB  = (const float*)d_in[45];
    const float* gateW = (const float*)d_in[46];
    const float* gateB = (const float*)d_in[47];
    const float* outW  = (const float*)d_in[48];
    const float* outB  = (const float*)d_in[49];

    const int N6 = BB * SS;            // 6144
    const int NF = BB * PRED;          // 768

    float* ws = (float*)d_ws;
    float* x    = ws;                    ws += (size_t)N6 * DIN;
    float* Hh   = ws;                    ws += (size_t)N6 * HH;
    float* Abuf = ws;                    ws += (size_t)N6 * HH;
    float* Qb   = ws;                    ws += (size_t)N6 * HH;
    float* Kb   = ws;                    ws += (size_t)N6 * HH;
    float* Vb   = ws;                    ws += (size_t)N6 * HH;
    float* Cb   = ws;                    ws += (size_t)N6 * HH;
    float* FFb  = ws;                    ws += (size_t)1536 * FF_;
    float* futh = ws;                    ws += (size_t)NF * HH;
    float* futx = ws;                    ws += (size_t)NF * DIN;
    float* futm = ws;                    ws += (size_t)NF * HH;
    float* futg = ws;                    ws += (size_t)NF * NE_;

    // 1. features -> x [6144,481] (includes input LN, eps 1e-5)
    build_x<<<N6, 512, 0, stream>>>(isf, hloc, psf, dayE, timeE, dowE, wdE, locE,
                                    ln_g, ln_b, x);

    // 2. proj = x @ inpW + inpB  -> Abuf (P)
    launch_gemm(x, inpW, inpB, Abuf, N6, DIN, HH, 0, nullptr, 0, stream);

    // 3. extra SelfAttention (16 heads, hd=48)
    launch_gemm(Abuf, saqW, saqB, Qb, N6, HH, HH, 0, nullptr, 0, stream);
    launch_gemm(Abuf, sakW, sakB, Kb, N6, HH, HH, 0, nullptr, 0, stream);
    launch_gemm(Abuf, savW, savB, Vb, N6, HH, HH, 0, nullptr, 0, stream);
    attn_f32<<<BB * 16 * SS, 128, 0, stream>>>(Qb, Kb, Vb, Cb, 16, 48, 1.f / sqrtf(48.f));
    launch_gemm(Cb, saoW, saoB, Qb, N6, HH, HH, 0, nullptr, 0, stream);
    ln768<<<N6, 256, 0, stream>>>(Hh, Qb, Abuf, nullptr, nullptr, salnG, salnB, 1e-5f);

    // 4. BERT embeddings: h = LN(h + pos + tt), eps 1e-12
    ln768<<<N6, 256, 0, stream>>>(Hh, Hh, nullptr, posE, ttE, belnG, belnB, 1e-12f);

    // 5. 12 encoder layers
    for (int i = 0; i < NL; ++i) {
        const size_t wo = (size_t)i * HH * HH;
        const size_t bo = (size_t)i * HH;
        launch_gemm(Hh, bqW + wo, bqB + bo, Qb, N6, HH, HH, 0, nullptr, 0, stream);
        launch_gemm(Hh, bkW + wo, bkB + bo, Kb, N6, HH, HH, 0, nullptr, 0, stream);
        launch_gemm(Hh, bvW + wo, bvB + bo, Vb, N6, HH, HH, 0, nullptr, 0, stream);
        attn_f32<<<BB * 12 * SS, 128, 0, stream>>>(Qb, Kb, Vb, Cb, 12, 64, 0.125f);
        launch_gemm(Cb, boW + wo, boB + bo, Qb, N6, HH, HH, 0, nullptr, 0, stream);
        ln768<<<N6, 256, 0, stream>>>(Abuf, Qb, Hh, nullptr, nullptr, balnG + bo, balnB + bo, 1e-12f);
        // FF, chunked over rows to bound ws (1536 rows x 3072)
        const size_t f1o = (size_t)i * HH * FF_;
        const size_t f2o = (size_t)i * FF_ * HH;
        for (int ch = 0; ch < 4; ++ch) {
            const size_t ro = (size_t)ch * 1536;
            launch_gemm(Abuf + ro * HH, bf1W + f1o, bf1B + (size_t)i * FF_, FFb,
                        1536, HH, FF_, 1, nullptr, 0, stream);
            launch_gemm(FFb, bf2W + f2o, bf2B + bo, Kb + ro * HH,
                        1536, FF_, HH, 0, nullptr, 0, stream);
        }
        ln768<<<N6, 256, 0, stream>>>(Hh, Kb, Abuf, nullptr, nullptr, bflnG + bo, bflnB + bo, 1e-12f);
    }

    // 6. future-token slice
    gather_fut<<<NF, 256, 0, stream>>>(Hh, futh, HH);
    gather_fut<<<NF, 256, 0, stream>>>(x, futx, DIN);

    // 7. residual path (also initializes MoE accumulator): futm = futx @ resW + resB
    launch_gemm(futx, resW, resB, futm, NF, DIN, HH, 0, nullptr, 0, stream);

    // 8. gate probs
    launch_gemm(futh, gateW, gateB, futg, NF, HH, NE_, 0, nullptr, 0, stream);
    gate_softmax<<<3, 256, 0, stream>>>(futg);

    // 9. dense soft-MoE, accumulated on top of res
    for (int e = 0; e < NE_; ++e)
        launch_gemm(futh, moeW + (size_t)e * HH * HH, moeB + (size_t)e * HH, futm,
                    NF, HH, HH, 2, futg + e, NE_, stream);

    // 10. logits for future tokens only: [768,768] @ [768,40000] + bias
    launch_gemm(futm, outW, outB, (float*)d_out, NF, HH, VV, 0, nullptr, 0, stream);
}

// Round 2
// 5492.087 us; speedup vs baseline: 10.0030x; 10.0030x over previous
//
#include <hip/hip_runtime.h>
#include <cstddef>
#include <math.h>

// ---------------- model dims ----------------
#define BB 16
#define HIST 336
#define PRED 48
#define SS 384
#define HH 768
#define NL 12
#define FF_ 3072
#define DIN 481
#define DINP 512
#define NE_ 8
#define VV 40000
#define VVP 40064

typedef __attribute__((ext_vector_type(8))) short short8;
typedef __attribute__((ext_vector_type(4))) float f32x4;
struct short4v { short x, y, z, w; };

__device__ __forceinline__ short f2bf(float f) {
    union { float f; unsigned u; } v; v.f = f;
    unsigned r = v.u + 0x7fff + ((v.u >> 16) & 1);
    return (short)(r >> 16);
}

using gvoid_t = const __attribute__((address_space(1))) void;
using svoid_t = __attribute__((address_space(3))) void;

// ================= bf16 MFMA GEMM =================
// C[N,M] = op(A[N,Kp]_bf16 @ Bt[M,Kp]_bf16^T + bias)
// OP 0: f32 write; OP 1: gelu f32 write; OP 4: gelu bf16 write
template<int OP>
__global__ __launch_bounds__(256)
void gemm_bf16(const short* __restrict__ A, const short* __restrict__ Bt,
               const float* __restrict__ bias, const float* __restrict__ bias2,
               const float* __restrict__ bias3,
               void* __restrict__ Cout, int Kp, int M, int ldc)
{
    __shared__ short As[2][128 * 64];
    __shared__ short Bs[2][128 * 64];
    const int tid  = threadIdx.x;
    const int lane = tid & 63;
    const int w    = tid >> 6;
    const int wr = w >> 1, wc = w & 1;
    const int lrow = lane & 15, lgrp = lane >> 4;
    const size_t rowBase = (size_t)blockIdx.y * 128;
    const size_t colBase = (size_t)blockIdx.x * 128;

    f32x4 acc[4][4];
    #pragma unroll
    for (int i = 0; i < 4; ++i)
        #pragma unroll
        for (int j = 0; j < 4; ++j)
            acc[i][j] = f32x4{0.f, 0.f, 0.f, 0.f};

    const int nkt = Kp >> 6;

    auto stage = [&](int buf, int kt) {
        const short* Ab = A  + rowBase * Kp + (size_t)kt * 64;
        const short* Bb = Bt + colBase * Kp + (size_t)kt * 64;
        #pragma unroll
        for (int c = 0; c < 4; ++c) {
            const int sidx = (w * 4 + c) * 64 + lane;
            const int r = sidx >> 3, sl = sidx & 7;
            const int sseg = sl ^ (r & 7);
            __builtin_amdgcn_global_load_lds(
                (gvoid_t*)(Ab + (size_t)r * Kp + sseg * 8),
                (svoid_t*)&As[buf][(w * 4 + c) * 512], 16, 0, 0);
            __builtin_amdgcn_global_load_lds(
                (gvoid_t*)(Bb + (size_t)r * Kp + sseg * 8),
                (svoid_t*)&Bs[buf][(w * 4 + c) * 512], 16, 0, 0);
        }
    };

    int cur = 0;
    stage(0, 0);
    __syncthreads();
    for (int kt = 0; kt < nkt; ++kt) {
        if (kt + 1 < nkt) stage(cur ^ 1, kt + 1);
        const short* as = As[cur];
        const short* bs = Bs[cur];
        #pragma unroll
        for (int kk = 0; kk < 2; ++kk) {
            short8 aF[4], bF[4];
            #pragma unroll
            for (int mi = 0; mi < 4; ++mi) {
                const int r = wr * 64 + mi * 16 + lrow;
                const int seg = (kk * 4 + lgrp) ^ (r & 7);
                aF[mi] = *(const short8*)&as[r * 64 + seg * 8];
            }
            #pragma unroll
            for (int ni = 0; ni < 4; ++ni) {
                const int r = wc * 64 + ni * 16 + lrow;
                const int seg = (kk * 4 + lgrp) ^ (r & 7);
                bF[ni] = *(const short8*)&bs[r * 64 + seg * 8];
            }
            #pragma unroll
            for (int mi = 0; mi < 4; ++mi)
                #pragma unroll
                for (int ni = 0; ni < 4; ++ni)
                    acc[mi][ni] = __builtin_amdgcn_mfma_f32_16x16x32_bf16(
                        aF[mi], bF[ni], acc[mi][ni], 0, 0, 0);
        }
        __syncthreads();
        cur ^= 1;
    }

    #pragma unroll
    for (int mi = 0; mi < 4; ++mi) {
        #pragma unroll
        for (int ni = 0; ni < 4; ++ni) {
            const int col = (int)colBase + wc * 64 + ni * 16 + lrow;
            if (col >= M) continue;
            const float* bp = bias; int bc = col;
            if (bias2 && col >= HH) {
                if (col < 2 * HH) { bp = bias2; bc = col - HH; }
                else              { bp = bias3; bc = col - 2 * HH; }
            }
            const float bz = bp[bc];
            #pragma unroll
            for (int j = 0; j < 4; ++j) {
                const size_t row = rowBase + wr * 64 + mi * 16 + lgrp * 4 + j;
                float v = acc[mi][ni][j] + bz;
                if (OP == 1 || OP == 4)
                    v = 0.5f * v * (1.f + erff(v * 0.70710678118654752f));
                if (OP == 4) ((short*)Cout)[row * ldc + col] = f2bf(v);
                else         ((float*)Cout)[row * ldc + col] = v;
            }
        }
    }
}

// ================= transpose + cvt: W[K,M] f32 -> Wt[Mp,Kp] bf16 (zero-pad) ===
__global__ __launch_bounds__(256)
void transpose_cvt(const float* __restrict__ W, short* __restrict__ Wt,
                   int K, int M, int Kp, int Mp)
{
    __shared__ float tile[32][33];
    const int m0 = blockIdx.x * 32, k0 = blockIdx.y * 32;
    const int tx = threadIdx.x, ty = threadIdx.y;
    #pragma unroll
    for (int i = 0; i < 4; ++i) {
        int k = k0 + ty + i * 8, m = m0 + tx;
        tile[ty + i * 8][tx] = (k < K && m < M) ? W[(size_t)k * M + m] : 0.f;
    }
    __syncthreads();
    #pragma unroll
    for (int i = 0; i < 4; ++i) {
        int m = m0 + ty + i * 8, k = k0 + tx;
        Wt[(size_t)m * Kp + k] = f2bf(tile[tx][ty + i * 8]);
    }
}

// ================= f32 -> bf16 (n multiple of 4) =================
__global__ __launch_bounds__(256)
void cvt_bf16(const float* __restrict__ src, short* __restrict__ dst, int n4)
{
    int i = blockIdx.x * 256 + threadIdx.x;
    if (i >= n4) return;
    float4 v = reinterpret_cast<const float4*>(src)[i];
    short4v o = { f2bf(v.x), f2bf(v.y), f2bf(v.z), f2bf(v.w) };
    reinterpret_cast<short4v*>(dst)[i] = o;
}

// ================= features -> LN -> bf16 x [6144,512] =================
__global__ __launch_bounds__(512)
void build_x(const int* __restrict__ isf, const int* __restrict__ hloc,
             const int* __restrict__ psf,
             const float* __restrict__ dayE, const float* __restrict__ timeE,
             const float* __restrict__ dowE, const float* __restrict__ wdE,
             const float* __restrict__ locE,
             const float* __restrict__ g, const float* __restrict__ b2,
             short* __restrict__ xb)
{
    const int tok = blockIdx.x;
    const int b = tok / SS, s = tok % SS;
    const int tid = threadIdx.x;
    __shared__ float red[512];
    const int* f;
    int loc = -1;
    if (s < HIST) { f = isf + (b * HIST + s) * 6; loc = hloc[b * HIST + s]; }
    else          { f = psf + (b * PRED + (s - HIST)) * 6; }
    float val = 0.f;
    if (tid < DIN) {
        int c = tid;
        if      (c < 64)  val = dayE[f[0] * 64 + c];
        else if (c < 128) val = timeE[f[1] * 64 + (c - 64)];
        else if (c < 192) val = dowE[f[3] * 64 + (c - 128)];
        else if (c < 224) val = wdE[f[4] * 32 + (c - 192)];
        else if (c == 224) val = (float)f[5];
        else val = (loc >= 0) ? locE[(size_t)loc * 256 + (c - 225)] : 0.f;
    }
    red[tid] = (tid < DIN) ? val : 0.f;
    __syncthreads();
    for (int o = 256; o > 0; o >>= 1) { if (tid < o) red[tid] += red[tid + o]; __syncthreads(); }
    float mean = red[0] / (float)DIN;
    __syncthreads();
    float d = (tid < DIN) ? (val - mean) : 0.f;
    red[tid] = d * d;
    __syncthreads();
    for (int o = 256; o > 0; o >>= 1) { if (tid < o) red[tid] += red[tid + o]; __syncthreads(); }
    float rstd = rsqrtf(red[0] / (float)DIN + 1e-5f);
    if (tid < DINP)
        xb[(size_t)tok * DINP + tid] =
            (tid < DIN) ? f2bf((val - mean) * rstd * g[tid] + b2[tid]) : (short)0;
}

// ================= LayerNorm(768) fused adds =================
__global__ __launch_bounds__(256)
void ln768(float* __restrict__ out, const float* __restrict__ in1,
           const float* __restrict__ in2, const float* __restrict__ pos,
           const float* __restrict__ tt,
           const float* __restrict__ g, const float* __restrict__ b2,
           float eps)
{
    const int D = HH;
    const int row = blockIdx.x;
    const int s = row % SS;
    __shared__ float buf[HH];
    __shared__ float red[256];
    const int tid = threadIdx.x;
    float partial = 0.f;
    #pragma unroll
    for (int i = 0; i < 3; ++i) {
        int c = tid + i * 256;
        float v = in1[(size_t)row * D + c];
        if (in2) v += in2[(size_t)row * D + c];
        if (pos) v += pos[(size_t)s * D + c];
        if (tt)  v += tt[c];
        buf[c] = v;
        partial += v;
    }
    red[tid] = partial; __syncthreads();
    for (int o = 128; o > 0; o >>= 1) { if (tid < o) red[tid] += red[tid + o]; __syncthreads(); }
    float mean = red[0] / (float)D;
    __syncthreads();
    float p2 = 0.f;
    #pragma unroll
    for (int i = 0; i < 3; ++i) { float d = buf[tid + i * 256] - mean; p2 += d * d; }
    red[tid] = p2; __syncthreads();
    for (int o = 128; o > 0; o >>= 1) { if (tid < o) red[tid] += red[tid + o]; __syncthreads(); }
    float rstd = rsqrtf(red[0] / (float)D + eps);
    #pragma unroll
    for (int i = 0; i < 3; ++i) {
        int c = tid + i * 256;
        out[(size_t)row * D + c] = (buf[c] - mean) * rstd * g[c] + b2[c];
    }
}

// ================= tiled flash attention =================
// block = (b, h, 64-row q tile); 256 threads = 16x16, each 4x4 micro-tile
template<int HD>
__global__ __launch_bounds__(256)
void attn_tile(const float* __restrict__ Q, const float* __restrict__ Kg,
               const float* __restrict__ Vg, float* __restrict__ O,
               int nh, int ldq, int ldo, float scale)
{
    constexpr int PHD = HD + 4;
    __shared__ float Qs[64][PHD];
    __shared__ float KPs[64][68];    // K tile, then reused for P (64 wide + pad)
    __shared__ float Vs[64][PHD];
    int idx = blockIdx.x;
    const int qt = idx % 6; idx /= 6;
    const int h = idx % nh; idx /= nh;
    const int b = idx;
    const int tid = threadIdx.x;
    const int tx = tid & 15, ty = tid >> 4;

    const float* Qbase = Q + ((size_t)(b * SS + qt * 64)) * ldq + h * HD;
    for (int i = tid; i < 64 * (HD / 4); i += 256) {
        int r = i / (HD / 4), c = (i % (HD / 4)) * 4;
        *(float4*)&Qs[r][c] = *(const float4*)&Qbase[(size_t)r * ldq + c];
    }

    float m_[4], l_[4], o_[4][4];
    #pragma unroll
    for (int i = 0; i < 4; ++i) {
        m_[i] = -1e30f; l_[i] = 0.f;
        #pragma unroll
        for (int j = 0; j < 4; ++j) o_[i][j] = 0.f;
    }

    for (int kt = 0; kt < 6; ++kt) {
        const float* Kb2 = Kg + ((size_t)(b * SS + kt * 64)) * ldq + h * HD;
        const float* Vb2 = Vg + ((size_t)(b * SS + kt * 64)) * ldq + h * HD;
        __syncthreads();               // prior P/V use complete before overwrite
        for (int i = tid; i < 64 * (HD / 4); i += 256) {
            int r = i / (HD / 4), c = (i % (HD / 4)) * 4;
            *(float4*)&KPs[r][c] = *(const float4*)&Kb2[(size_t)r * ldq + c];
            *(float4*)&Vs[r][c]  = *(const float4*)&Vb2[(size_t)r * ldq + c];
        }
        __syncthreads();
        float sacc[4][4];
        #pragma unroll
        for (int i = 0; i < 4; ++i)
            #pragma unroll
            for (int j = 0; j < 4; ++j) sacc[i][j] = 0.f;
        for (int c = 0; c < HD; c += 4) {
            float4 a4[4], b4[4];
            #pragma unroll
            for (int i = 0; i < 4; ++i) a4[i] = *(const float4*)&Qs[ty * 4 + i][c];
            #pragma unroll
            for (int j = 0; j < 4; ++j) b4[j] = *(const float4*)&KPs[tx * 4 + j][c];
            #pragma unroll
            for (int i = 0; i < 4; ++i)
                #pragma unroll
                for (int j = 0; j < 4; ++j)
                    sacc[i][j] += a4[i].x * b4[j].x + a4[i].y * b4[j].y
                                + a4[i].z * b4[j].z + a4[i].w * b4[j].w;
        }
        __syncthreads();               // scores done; safe to overwrite KPs with P
        #pragma unroll
        for (int i = 0; i < 4; ++i) {
            float tm = -1e30f;
            #pragma unroll
            for (int j = 0; j < 4; ++j) { sacc[i][j] *= scale; tm = fmaxf(tm, sacc[i][j]); }
            #pragma unroll
            for (int s2 = 1; s2 < 16; s2 <<= 1) tm = fmaxf(tm, __shfl_xor(tm, s2));
            float mn = fmaxf(m_[i], tm);
            float r2 = __expf(m_[i] - mn);
            float p0 = __expf(sacc[i][0] - mn), p1 = __expf(sacc[i][1] - mn);
            float p2 = __expf(sacc[i][2] - mn), p3 = __expf(sacc[i][3] - mn);
            float ps = p0 + p1 + p2 + p3;
            #pragma unroll
            for (int s2 = 1; s2 < 16; s2 <<= 1) ps += __shfl_xor(ps, s2);
            l_[i] = l_[i] * r2 + ps;
            m_[i] = mn;
            #pragma unroll
            for (int j = 0; j < 4; ++j) o_[i][j] *= r2;
            *(float4*)&KPs[ty * 4 + i][tx * 4] = make_float4(p0, p1, p2, p3);
        }
        __syncthreads();
        if (tx * 4 < HD) {
            for (int kc = 0; kc < 64; ++kc) {
                float4 v4 = *(const float4*)&Vs[kc][tx * 4];
                #pragma unroll
                for (int i = 0; i < 4; ++i) {
                    float p = KPs[ty * 4 + i][kc];
                    o_[i][0] = fmaf(p, v4.x, o_[i][0]);
                    o_[i][1] = fmaf(p, v4.y, o_[i][1]);
                    o_[i][2] = fmaf(p, v4.z, o_[i][2]);
                    o_[i][3] = fmaf(p, v4.w, o_[i][3]);
                }
            }
        }
    }
    if (tx * 4 < HD) {
        #pragma unroll
        for (int i = 0; i < 4; ++i) {
            float inv = 1.f / l_[i];
            float4 ov = make_float4(o_[i][0] * inv, o_[i][1] * inv,
                                    o_[i][2] * inv, o_[i][3] * inv);
            *(float4*)&O[((size_t)(b * SS + qt * 64) + ty * 4 + i) * ldo + h * HD + tx * 4] = ov;
        }
    }
}

// ================= gathers =================
__global__ void gather_fut_f32(const float* __restrict__ src, float* __restrict__ dst, int D)
{
    const int r = blockIdx.x;
    const int b = r / PRED, t = r % PRED;
    const int srow = b * SS + HIST + t;
    for (int c = threadIdx.x; c < D; c += blockDim.x)
        dst[(size_t)r * D + c] = src[(size_t)srow * D + c];
}
__global__ void gather_fut_b16(const short* __restrict__ src, short* __restrict__ dst, int D)
{
    const int r = blockIdx.x;
    const int b = r / PRED, t = r % PRED;
    const int srow = b * SS + HIST + t;
    for (int c = threadIdx.x; c < D; c += blockDim.x)
        dst[(size_t)r * D + c] = src[(size_t)srow * D + c];
}

// ================= gate =================
__global__ __launch_bounds__(256)
void gate_kernel(const float* __restrict__ Xf, const float* __restrict__ Wg,
                 const float* __restrict__ bg, float* __restrict__ out)
{
    const int row = blockIdx.x;
    const int tid = threadIdx.x;
    float a[NE_] = {};
    for (int k = tid; k < HH; k += 256) {
        float xv = Xf[(size_t)row * HH + k];
        #pragma unroll
        for (int e = 0; e < NE_; ++e) a[e] = fmaf(xv, Wg[k * NE_ + e], a[e]);
    }
    __shared__ float red[256];
    #pragma unroll
    for (int e = 0; e < NE_; ++e) {
        red[tid] = a[e]; __syncthreads();
        for (int o = 128; o > 0; o >>= 1) { if (tid < o) red[tid] += red[tid + o]; __syncthreads(); }
        if (tid == 0) out[(size_t)row * NE_ + e] = red[0] + bg[e];
        __syncthreads();
    }
}

__global__ void gate_softmax(float* __restrict__ gate)
{
    const int r = blockIdx.x * blockDim.x + threadIdx.x;
    if (r >= BB * PRED) return;
    float* p = gate + (size_t)r * NE_;
    float mx = p[0];
    for (int e = 1; e < NE_; ++e) mx = fmaxf(mx, p[e]);
    float s = 0.f, v[NE_];
    for (int e = 0; e < NE_; ++e) { v[e] = __expf(p[e] - mx); s += v[e]; }
    for (int e = 0; e < NE_; ++e) p[e] = v[e] / s;
}

// ================= MoE gated reduce: futm += sum_e g[e]*eo[row][e*768+c] ====
__global__ __launch_bounds__(256)
void moe_reduce(const float* __restrict__ eo, const float* __restrict__ gp,
                float* __restrict__ futm)
{
    const int row = blockIdx.x;
    float g[NE_];
    #pragma unroll
    for (int e = 0; e < NE_; ++e) g[e] = gp[row * NE_ + e];
    for (int c = threadIdx.x; c < HH; c += 256) {
        float s = futm[(size_t)row * HH + c];
        #pragma unroll
        for (int e = 0; e < NE_; ++e)
            s = fmaf(g[e], eo[(size_t)row * (NE_ * HH) + e * HH + c], s);
        futm[(size_t)row * HH + c] = s;
    }
}

// ================= host =================
static inline void tcvt(const float* W, short* Wt, int K, int M, int Kp, int Mp,
                        hipStream_t stream)
{
    dim3 g(Mp / 32, Kp / 32), b(32, 8);
    transpose_cvt<<<g, b, 0, stream>>>(W, Wt, K, M, Kp, Mp);
}
static inline void cvt(const float* src, short* dst, size_t n, hipStream_t stream)
{
    int n4 = (int)(n / 4);
    cvt_bf16<<<(n4 + 255) / 256, 256, 0, stream>>>(src, dst, n4);
}

extern "C" void kernel_launch(void* const* d_in, const int* in_sizes, int n_in,
                              void* d_out, int out_size, void* d_ws, size_t ws_size,
                              hipStream_t stream)
{
    const int*   isf   = (const int*)  d_in[0];
    const int*   hloc  = (const int*)  d_in[1];
    const int*   psf   = (const int*)  d_in[2];
    const float* dayE  = (const float*)d_in[3];
    const float* timeE = (const float*)d_in[4];
    const float* dowE  = (const float*)d_in[5];
    const float* wdE   = (const float*)d_in[6];
    const float* locE  = (const float*)d_in[7];
    const float* ln_g  = (const float*)d_in[8];
    const float* ln_b  = (const float*)d_in[9];
    const float* inpW  = (const float*)d_in[10];
    const float* inpB  = (const float*)d_in[11];
    const float* resW  = (const float*)d_in[12];
    const float* resB  = (const float*)d_in[13];
    const float* saqW  = (const float*)d_in[14];
    const float* sakW  = (const float*)d_in[15];
    const float* savW  = (const float*)d_in[16];
    const float* saoW  = (const float*)d_in[17];
    const float* saqB  = (const float*)d_in[18];
    const float* sakB  = (const float*)d_in[19];
    const float* savB  = (const float*)d_in[20];
    const float* saoB  = (const float*)d_in[21];
    const float* salnG = (const float*)d_in[22];
    const float* salnB = (const float*)d_in[23];
    const float* posE  = (const float*)d_in[24];
    const float* ttE   = (const float*)d_in[25];
    const float* belnG = (const float*)d_in[26];
    const float* belnB = (const float*)d_in[27];
    const float* bqW   = (const float*)d_in[28];
    const float* bkW   = (const float*)d_in[29];
    const float* bvW   = (const float*)d_in[30];
    const float* boW   = (const float*)d_in[31];
    const float* bqB   = (const float*)d_in[32];
    const float* bkB   = (const float*)d_in[33];
    const float* bvB   = (const float*)d_in[34];
    const float* boB   = (const float*)d_in[35];
    const float* balnG = (const float*)d_in[36];
    const float* balnB = (const float*)d_in[37];
    const float* bf1W  = (const float*)d_in[38];
    const float* bf1B  = (const float*)d_in[39];
    const float* bf2W  = (const float*)d_in[40];
    const float* bf2B  = (const float*)d_in[41];
    const float* bflnG = (const float*)d_in[42];
    const float* bflnB = (const float*)d_in[43];
    const float* moeW  = (const float*)d_in[44];
    const float* moeB  = (const float*)d_in[45];
    const float* gateW = (const float*)d_in[46];
    const float* gateB = (const float*)d_in[47];
    const float* outW  = (const float*)d_in[48];
    const float* outB  = (const float*)d_in[49];

    const int N6 = BB * SS;            // 6144
    const int NF = BB * PRED;          // 768

    char* base = (char*)d_ws;
    size_t off = 0;
    auto alloc = [&](size_t bytes) -> void* {
        void* p = base + off;
        off = (off + bytes + 255) & ~(size_t)255;
        return p;
    };

    short* xb     = (short*)alloc((size_t)N6 * DINP * 2);
    float* Hh     = (float*)alloc((size_t)N6 * HH * 4);
    float* Abuf   = (float*)alloc((size_t)N6 * HH * 4);
    float* QKV    = (float*)alloc((size_t)N6 * 3 * HH * 4);   // Q|K|V fused, ld=2304
    float* Cb     = (float*)alloc((size_t)N6 * HH * 4);
    short* hb     = (short*)alloc((size_t)N6 * HH * 2);
    short* ffb    = (short*)alloc((size_t)N6 * FF_ * 2);
    short* inpWt  = (short*)alloc((size_t)HH * DINP * 2);
    short* resWt  = (short*)alloc((size_t)HH * DINP * 2);
    short* saWt   = (short*)alloc((size_t)3 * HH * HH * 2);   // fused qkv
    short* saoWt  = (short*)alloc((size_t)HH * HH * 2);
    short* lqkvWt = (short*)alloc((size_t)3 * HH * HH * 2);
    short* loWt   = (short*)alloc((size_t)HH * HH * 2);
    short* lf1Wt  = (short*)alloc((size_t)FF_ * HH * 2);
    short* lf2Wt  = (short*)alloc((size_t)HH * FF_ * 2);
    float* futh   = (float*)alloc((size_t)NF * HH * 4);
    float* futm   = (float*)alloc((size_t)NF * HH * 4);
    float* futg   = (float*)alloc((size_t)NF * NE_ * 4);

    // overlay into QKV+Cb region after the encoder loop (dead by then)
    short* outWt = (short*)QKV;                       // [40064][768]
    short* moeWt = outWt + (size_t)VVP * HH;          // [6144][768]
    short* futhb = moeWt + (size_t)NE_ * HH * HH;
    short* futxb = futhb + (size_t)NF * HH;
    short* futmb = futxb + (size_t)NF * DINP;

    // ---- features + input LN -> bf16 x ----
    build_x<<<N6, 512, 0, stream>>>(isf, hloc, psf, dayE, timeE, dowE, wdE, locE,
                                    ln_g, ln_b, xb);

    // ---- upfront weight prep ----
    tcvt(inpW, inpWt, DIN, HH, DINP, HH, stream);
    tcvt(resW, resWt, DIN, HH, DINP, HH, stream);
    tcvt(saqW, saWt,                      HH, HH, HH, HH, stream);
    tcvt(sakW, saWt + (size_t)HH * HH,    HH, HH, HH, HH, stream);
    tcvt(savW, saWt + (size_t)2 * HH * HH,HH, HH, HH, HH, stream);
    tcvt(saoW, saoWt, HH, HH, HH, HH, stream);

    // ---- proj = LN(x) @ inpW ----
    gemm_bf16<0><<<dim3(HH / 128, N6 / 128), 256, 0, stream>>>(
        xb, inpWt, inpB, nullptr, nullptr, Abuf, DINP, HH, HH);

    // ---- SA block (16 heads, hd=48) ----
    cvt(Abuf, hb, (size_t)N6 * HH, stream);
    gemm_bf16<0><<<dim3(3 * HH / 128, N6 / 128), 256, 0, stream>>>(
        hb, saWt, saqB, sakB, savB, QKV, HH, 3 * HH, 3 * HH);
    attn_tile<48><<<BB * 16 * 6, 256, 0, stream>>>(
        QKV, QKV + HH, QKV + 2 * HH, Cb, 16, 3 * HH, HH, 1.f / sqrtf(48.f));
    cvt(Cb, hb, (size_t)N6 * HH, stream);
    gemm_bf16<0><<<dim3(HH / 128, N6 / 128), 256, 0, stream>>>(
        hb, saoWt, saoB, nullptr, nullptr, Cb, HH, HH, HH);
    ln768<<<N6, 256, 0, stream>>>(Hh, Cb, Abuf, nullptr, nullptr, salnG, salnB, 1e-5f);

    // ---- BERT embeddings LN ----
    ln768<<<N6, 256, 0, stream>>>(Hh, Hh, nullptr, posE, ttE, belnG, belnB, 1e-12f);

    // ---- 12 encoder layers ----
    for (int i = 0; i < NL; ++i) {
        const size_t wo = (size_t)i * HH * HH;
        const size_t bo = (size_t)i * HH;
        tcvt(bqW + wo, lqkvWt,                       HH, HH, HH, HH, stream);
        tcvt(bkW + wo, lqkvWt + (size_t)HH * HH,     HH, HH, HH, HH, stream);
        tcvt(bvW + wo, lqkvWt + (size_t)2 * HH * HH, HH, HH, HH, HH, stream);
        tcvt(boW + wo, loWt, HH, HH, HH, HH, stream);
        tcvt(bf1W + (size_t)i * HH * FF_, lf1Wt, HH, FF_, HH, FF_, stream);
        tcvt(bf2W + (size_t)i * FF_ * HH, lf2Wt, FF_, HH, FF_, HH, stream);

        cvt(Hh, hb, (size_t)N6 * HH, stream);
        gemm_bf16<0><<<dim3(3 * HH / 128, N6 / 128), 256, 0, stream>>>(
            hb, lqkvWt, bqB + bo, bkB + bo, bvB + bo, QKV, HH, 3 * HH, 3 * HH);
        attn_tile<64><<<BB * 12 * 6, 256, 0, stream>>>(
            QKV, QKV + HH, QKV + 2 * HH, Cb, 12, 3 * HH, HH, 0.125f);
        cvt(Cb, hb, (size_t)N6 * HH, stream);
        gemm_bf16<0><<<dim3(HH / 128, N6 / 128), 256, 0, stream>>>(
            hb, loWt, boB + bo, nullptr, nullptr, Cb, HH, HH, HH);
        ln768<<<N6, 256, 0, stream>>>(Abuf, Cb, Hh, nullptr, nullptr,
                                      balnG + bo, balnB + bo, 1e-12f);
        cvt(Abuf, hb, (size_t)N6 * HH, stream);
        gemm_bf16<4><<<dim3(FF_ / 128, N6 / 128), 256, 0, stream>>>(
            hb, lf1Wt, bf1B + (size_t)i * FF_, nullptr, nullptr, ffb, HH, FF_, FF_);
        gemm_bf16<0><<<dim3(HH / 128, N6 / 128), 256, 0, stream>>>(
            ffb, lf2Wt, bf2B + bo, nullptr, nullptr, Cb, FF_, HH, HH);
        ln768<<<N6, 256, 0, stream>>>(Hh, Cb, Abuf, nullptr, nullptr,
                                      bflnG + bo, bflnB + bo, 1e-12f);
    }

    // ---- future slice ----
    gather_fut_f32<<<NF, 256, 0, stream>>>(Hh, futh, HH);
    gather_fut_b16<<<NF, 256, 0, stream>>>(xb, futxb, DINP);

    // ---- residual path ----
    gemm_bf16<0><<<dim3(HH / 128, NF / 128), 256, 0, stream>>>(
        futxb, resWt, resB, nullptr, nullptr, futm, DINP, HH, HH);

    // ---- gate ----
    gate_kernel<<<NF, 256, 0, stream>>>(futh, gateW, gateB, futg);
    gate_softmax<<<3, 256, 0, stream>>>(futg);

    // ---- MoE: all 8 experts fused, eo -> Hh region (dead) ----
    cvt(futh, futhb, (size_t)NF * HH, stream);
    for (int e = 0; e < NE_; ++e)
        tcvt(moeW + (size_t)e * HH * HH, moeWt + (size_t)e * HH * HH,
             HH, HH, HH, HH, stream);
    gemm_bf16<1><<<dim3(NE_ * HH / 128, NF / 128), 256, 0, stream>>>(
        futhb, moeWt, moeB, nullptr, nullptr, Hh, HH, NE_ * HH, NE_ * HH);
    moe_reduce<<<NF, 256, 0, stream>>>(Hh, futg, futm);

    // ---- head: logits for future tokens ----
    cvt(futm, futmb, (size_t)NF * HH, stream);
    tcvt(outW, outWt, HH, VV, HH, VVP, stream);
    gemm_bf16<0><<<dim3(VVP / 128, NF / 128), 256, 0, stream>>>(
        futmb, outWt, outB, nullptr, nullptr, (float*)d_out, HH, VV, VV);
}

// Round 3
// 3734.770 us; speedup vs baseline: 14.7097x; 1.4705x over previous
//
#include <hip/hip_runtime.h>
#include <cstddef>
#include <math.h>

// ---------------- model dims ----------------
#define BB 16
#define HIST 336
#define PRED 48
#define SS 384
#define HH 768
#define NL 12
#define FF_ 3072
#define DIN 481
#define DINP 512
#define NE_ 8
#define VV 40000
#define VVP 40064

typedef __attribute__((ext_vector_type(8))) short short8;
typedef __attribute__((ext_vector_type(4))) float f32x4;
struct short4v { short x, y, z, w; };

__device__ __forceinline__ short f2bf(float f) {
    union { float f; unsigned u; } v; v.f = f;
    unsigned r = v.u + 0x7fff + ((v.u >> 16) & 1);
    return (short)(r >> 16);
}

using gvoid_t = const __attribute__((address_space(1))) void;
using svoid_t = __attribute__((address_space(3))) void;

// ================= bf16 MFMA GEMM =================
// C[N,M] = op(A[N,Kp]_bf16 @ Bt[M,Kp]_bf16^T + bias)
// OP 0: f32; OP 1: gelu f32; OP 4: gelu bf16; OP 5: bf16; OP 6: f32 + bf16 dual
template<int OP>
__global__ __launch_bounds__(256)
void gemm_bf16(const short* __restrict__ A, const short* __restrict__ Bt,
               const float* __restrict__ bias, const float* __restrict__ bias2,
               const float* __restrict__ bias3,
               void* __restrict__ Cout, void* __restrict__ Cout2,
               int Kp, int M, int ldc)
{
    __shared__ short As[2][128 * 64];
    __shared__ short Bs[2][128 * 64];
    const int tid  = threadIdx.x;
    const int lane = tid & 63;
    const int w    = tid >> 6;
    const int wr = w >> 1, wc = w & 1;
    const int lrow = lane & 15, lgrp = lane >> 4;
    const size_t rowBase = (size_t)blockIdx.y * 128;
    const size_t colBase = (size_t)blockIdx.x * 128;

    f32x4 acc[4][4];
    #pragma unroll
    for (int i = 0; i < 4; ++i)
        #pragma unroll
        for (int j = 0; j < 4; ++j)
            acc[i][j] = f32x4{0.f, 0.f, 0.f, 0.f};

    const int nkt = Kp >> 6;

    auto stage = [&](int buf, int kt) {
        const short* Ab = A  + rowBase * Kp + (size_t)kt * 64;
        const short* Bb = Bt + colBase * Kp + (size_t)kt * 64;
        #pragma unroll
        for (int c = 0; c < 4; ++c) {
            const int sidx = (w * 4 + c) * 64 + lane;
            const int r = sidx >> 3, sl = sidx & 7;
            const int sseg = sl ^ (r & 7);
            __builtin_amdgcn_global_load_lds(
                (gvoid_t*)(Ab + (size_t)r * Kp + sseg * 8),
                (svoid_t*)&As[buf][(w * 4 + c) * 512], 16, 0, 0);
            __builtin_amdgcn_global_load_lds(
                (gvoid_t*)(Bb + (size_t)r * Kp + sseg * 8),
                (svoid_t*)&Bs[buf][(w * 4 + c) * 512], 16, 0, 0);
        }
    };

    int cur = 0;
    stage(0, 0);
    __syncthreads();
    for (int kt = 0; kt < nkt; ++kt) {
        if (kt + 1 < nkt) stage(cur ^ 1, kt + 1);
        const short* as = As[cur];
        const short* bs = Bs[cur];
        #pragma unroll
        for (int kk = 0; kk < 2; ++kk) {
            short8 aF[4], bF[4];
            #pragma unroll
            for (int mi = 0; mi < 4; ++mi) {
                const int r = wr * 64 + mi * 16 + lrow;
                const int seg = (kk * 4 + lgrp) ^ (r & 7);
                aF[mi] = *(const short8*)&as[r * 64 + seg * 8];
            }
            #pragma unroll
            for (int ni = 0; ni < 4; ++ni) {
                const int r = wc * 64 + ni * 16 + lrow;
                const int seg = (kk * 4 + lgrp) ^ (r & 7);
                bF[ni] = *(const short8*)&bs[r * 64 + seg * 8];
            }
            #pragma unroll
            for (int mi = 0; mi < 4; ++mi)
                #pragma unroll
                for (int ni = 0; ni < 4; ++ni)
                    acc[mi][ni] = __builtin_amdgcn_mfma_f32_16x16x32_bf16(
                        aF[mi], bF[ni], acc[mi][ni], 0, 0, 0);
        }
        __syncthreads();
        cur ^= 1;
    }

    #pragma unroll
    for (int mi = 0; mi < 4; ++mi) {
        #pragma unroll
        for (int ni = 0; ni < 4; ++ni) {
            const int col = (int)colBase + wc * 64 + ni * 16 + lrow;
            if (col >= M) continue;
            const float* bp = bias; int bc = col;
            if (bias2 && col >= HH) {
                if (col < 2 * HH) { bp = bias2; bc = col - HH; }
                else              { bp = bias3; bc = col - 2 * HH; }
            }
            const float bz = bp[bc];
            #pragma unroll
            for (int j = 0; j < 4; ++j) {
                const size_t row = rowBase + wr * 64 + mi * 16 + lgrp * 4 + j;
                float v = acc[mi][ni][j] + bz;
                if (OP == 1 || OP == 4)
                    v = 0.5f * v * (1.f + erff(v * 0.70710678118654752f));
                if (OP == 4 || OP == 5) ((short*)Cout)[row * ldc + col] = f2bf(v);
                else                    ((float*)Cout)[row * ldc + col] = v;
                if (OP == 6)            ((short*)Cout2)[row * ldc + col] = f2bf(v);
            }
        }
    }
}

// ================= bf16 MFMA flash attention =================
// block = (b, h, 64-q-row tile); 256 threads = 4 waves, 16 q-rows each
template<int HD>
__global__ __launch_bounds__(256)
void attn_mfma(const short* __restrict__ Qg, const short* __restrict__ Kg,
               const short* __restrict__ Vg, short* __restrict__ Og,
               int nh, int ldq, int ldo, float scale)
{
    constexpr int NI = HD / 16;     // output d frags
    constexpr int SEGS = HD / 8;    // valid 8-short segments per row
    __shared__ short Qs[64 * 64];
    __shared__ short Ks[64 * 64];
    __shared__ short Vt[64 * 72];   // transposed V: [d][k], pad 8
    __shared__ short Ps[4][16 * 80];// per-wave P tile: [16 q][64 k], pad 16
    int idx = blockIdx.x;
    const int qt = idx % 6; idx /= 6;
    const int h = idx % nh; idx /= nh;
    const int b = idx;
    const int tid = threadIdx.x;
    const int lane = tid & 63;
    const int w = tid >> 6;
    const int lrow = lane & 15, lgrp = lane >> 4;

    // ---- stage Q once: rows 64, cols 64, zero-filled beyond HD ----
    const short* Qbase = Qg + ((size_t)(b * SS + qt * 64)) * ldq + h * HD;
    #pragma unroll
    for (int t = 0; t < 2; ++t) {
        const int i = tid + t * 256;
        const int r = i >> 3, sg = i & 7;
        short8 v = {0, 0, 0, 0, 0, 0, 0, 0};
        if (sg < SEGS) v = *(const short8*)(Qbase + (size_t)r * ldq + sg * 8);
        *(short8*)&Qs[r * 64 + (sg ^ (r & 7)) * 8] = v;
    }

    float m_[4], l_[4];
    f32x4 o_[NI];
    #pragma unroll
    for (int j = 0; j < 4; ++j) { m_[j] = -1e30f; l_[j] = 0.f; }
    #pragma unroll
    for (int ni = 0; ni < NI; ++ni) o_[ni] = f32x4{0.f, 0.f, 0.f, 0.f};

    for (int kt = 0; kt < 6; ++kt) {
        const short* Kb2 = Kg + ((size_t)(b * SS + kt * 64)) * ldq + h * HD;
        const short* Vb2 = Vg + ((size_t)(b * SS + kt * 64)) * ldq + h * HD;
        __syncthreads();   // prior-iter reads of Ks/Vt done (and Q staged, kt=0)
        // K tile via global_load_lds, XOR-swizzled (cols>=HD garbage: Q is 0 there)
        #pragma unroll
        for (int c = 0; c < 2; ++c) {
            const int r = (w * 2 + c) * 8 + (lane >> 3);
            const int sg = (lane & 7) ^ (r & 7);
            __builtin_amdgcn_global_load_lds(
                (gvoid_t*)(Kb2 + (size_t)r * ldq + sg * 8),
                (svoid_t*)&Ks[(w * 2 + c) * 512], 16, 0, 0);
        }
        // V tile transposed: Vt[d][k], only d < HD
        for (int i = tid; i < 64 * SEGS; i += 256) {
            const int k = i & 63, sg = i >> 6;
            short8 v = *(const short8*)(Vb2 + (size_t)k * ldq + sg * 8);
            #pragma unroll
            for (int j2 = 0; j2 < 8; ++j2)
                Vt[(sg * 8 + j2) * 72 + k] = v[j2];
        }
        __syncthreads();

        // ---- S = Q @ K^T (wave's 16 q rows x 64 k cols) ----
        f32x4 s[4];
        #pragma unroll
        for (int ni = 0; ni < 4; ++ni) s[ni] = f32x4{0.f, 0.f, 0.f, 0.f};
        #pragma unroll
        for (int kk = 0; kk < 2; ++kk) {
            const int ra = w * 16 + lrow;
            const short8 aF = *(const short8*)&Qs[ra * 64 + ((kk * 4 + lgrp) ^ (ra & 7)) * 8];
            #pragma unroll
            for (int ni = 0; ni < 4; ++ni) {
                const int rb = ni * 16 + lrow;
                const short8 bF = *(const short8*)&Ks[rb * 64 + ((kk * 4 + lgrp) ^ (rb & 7)) * 8];
                s[ni] = __builtin_amdgcn_mfma_f32_16x16x32_bf16(aF, bF, s[ni], 0, 0, 0);
            }
        }
        #pragma unroll
        for (int ni = 0; ni < 4; ++ni)
            #pragma unroll
            for (int j = 0; j < 4; ++j) s[ni][j] *= scale;

        // ---- online softmax per q-row (row = lgrp*4+j, cols = ni*16+lrow) ----
        #pragma unroll
        for (int j = 0; j < 4; ++j) {
            float tm = fmaxf(fmaxf(s[0][j], s[1][j]), fmaxf(s[2][j], s[3][j]));
            #pragma unroll
            for (int d = 1; d < 16; d <<= 1) tm = fmaxf(tm, __shfl_xor(tm, d));
            const float mn = fmaxf(m_[j], tm);
            const float r2 = __expf(m_[j] - mn);
            float p[4], ps = 0.f;
            #pragma unroll
            for (int ni = 0; ni < 4; ++ni) { p[ni] = __expf(s[ni][j] - mn); ps += p[ni]; }
            #pragma unroll
            for (int d = 1; d < 16; d <<= 1) ps += __shfl_xor(ps, d);
            l_[j] = l_[j] * r2 + ps;
            m_[j] = mn;
            #pragma unroll
            for (int ni = 0; ni < NI; ++ni) o_[ni][j] *= r2;
            #pragma unroll
            for (int ni = 0; ni < 4; ++ni)
                Ps[w][(lgrp * 4 + j) * 80 + ni * 16 + lrow] = f2bf(p[ni]);
        }

        // ---- O += P @ V ----
        #pragma unroll
        for (int kk = 0; kk < 2; ++kk) {
            const short8 aP = *(const short8*)&Ps[w][lrow * 80 + kk * 32 + lgrp * 8];
            #pragma unroll
            for (int ni = 0; ni < NI; ++ni) {
                const int d0 = ni * 16 + lrow;
                const short8 bV = *(const short8*)&Vt[d0 * 72 + (kk * 4 + lgrp) * 8];
                o_[ni] = __builtin_amdgcn_mfma_f32_16x16x32_bf16(aP, bV, o_[ni], 0, 0, 0);
            }
        }
    }

    // ---- epilogue: O = o / l, bf16 ----
    const size_t orow0 = (size_t)(b * SS + qt * 64 + w * 16);
    #pragma unroll
    for (int j = 0; j < 4; ++j) {
        const float inv = 1.f / l_[j];
        #pragma unroll
        for (int ni = 0; ni < NI; ++ni)
            Og[(orow0 + lgrp * 4 + j) * ldo + h * HD + ni * 16 + lrow] =
                f2bf(o_[ni][j] * inv);
    }
}

// ======== batched transpose+cvt: W[K,M] f32 -> Wt[Mp,Kp] bf16, z-batched ====
__global__ __launch_bounds__(256)
void transpose_cvt_b(const float* __restrict__ W, short* __restrict__ Wt,
                     int K, int M, int Kp, size_t sStride, size_t dStride)
{
    __shared__ float tile[32][33];
    const float* src = W + blockIdx.z * sStride;
    short* dst = Wt + blockIdx.z * dStride;
    const int m0 = blockIdx.x * 32, k0 = blockIdx.y * 32;
    const int tx = threadIdx.x, ty = threadIdx.y;
    #pragma unroll
    for (int i = 0; i < 4; ++i) {
        int k = k0 + ty + i * 8, m = m0 + tx;
        tile[ty + i * 8][tx] = (k < K && m < M) ? src[(size_t)k * M + m] : 0.f;
    }
    __syncthreads();
    #pragma unroll
    for (int i = 0; i < 4; ++i) {
        int m = m0 + ty + i * 8, k = k0 + tx;
        dst[(size_t)m * Kp + k] = f2bf(tile[tx][ty + i * 8]);
    }
}

// ======== per-layer weight prep: qkv(3) + o + f1 + f2 in one launch ========
__global__ __launch_bounds__(256)
void prep_layer_w(const float* __restrict__ bq, const float* __restrict__ bk,
                  const float* __restrict__ bv, const float* __restrict__ bo,
                  const float* __restrict__ f1, const float* __restrict__ f2,
                  short* __restrict__ qkvT, short* __restrict__ oT,
                  short* __restrict__ f1T, short* __restrict__ f2T)
{
    __shared__ float tile[32][33];
    int id = blockIdx.x;
    const float* src; short* dst; int K, M, tm, tk;
    if (id < 1728) {
        const int mat = id / 576, r = id % 576;
        src = mat == 0 ? bq : (mat == 1 ? bk : bv);
        dst = qkvT + (size_t)mat * HH * HH;
        K = HH; M = HH; tm = r % 24; tk = r / 24;
    } else if (id < 2304) {
        const int r = id - 1728;
        src = bo; dst = oT; K = HH; M = HH; tm = r % 24; tk = r / 24;
    } else if (id < 4608) {
        const int r = id - 2304;
        src = f1; dst = f1T; K = HH; M = FF_; tm = r % 96; tk = r / 96;
    } else {
        const int r = id - 4608;
        src = f2; dst = f2T; K = FF_; M = HH; tm = r % 24; tk = r / 24;
    }
    const int m0 = tm * 32, k0 = tk * 32;
    const int tx = threadIdx.x & 31, ty = threadIdx.x >> 5;
    #pragma unroll
    for (int i = 0; i < 4; ++i) {
        int k = k0 + ty + i * 8, m = m0 + tx;
        tile[ty + i * 8][tx] = src[(size_t)k * M + m];
    }
    __syncthreads();
    #pragma unroll
    for (int i = 0; i < 4; ++i) {
        int m = m0 + ty + i * 8, k = k0 + tx;
        dst[(size_t)m * K + k] = f2bf(tile[tx][ty + i * 8]);
    }
}

// ================= f32 -> bf16 =================
__global__ __launch_bounds__(256)
void cvt_bf16(const float* __restrict__ src, short* __restrict__ dst, int n4)
{
    int i = blockIdx.x * 256 + threadIdx.x;
    if (i >= n4) return;
    float4 v = reinterpret_cast<const float4*>(src)[i];
    short4v o = { f2bf(v.x), f2bf(v.y), f2bf(v.z), f2bf(v.w) };
    reinterpret_cast<short4v*>(dst)[i] = o;
}

// ================= features -> LN -> bf16 x [6144,512] =================
__global__ __launch_bounds__(512)
void build_x(const int* __restrict__ isf, const int* __restrict__ hloc,
             const int* __restrict__ psf,
             const float* __restrict__ dayE, const float* __restrict__ timeE,
             const float* __restrict__ dowE, const float* __restrict__ wdE,
             const float* __restrict__ locE,
             const float* __restrict__ g, const float* __restrict__ b2,
             short* __restrict__ xb)
{
    const int tok = blockIdx.x;
    const int b = tok / SS, s = tok % SS;
    const int tid = threadIdx.x;
    __shared__ float red[512];
    const int* f;
    int loc = -1;
    if (s < HIST) { f = isf + (b * HIST + s) * 6; loc = hloc[b * HIST + s]; }
    else          { f = psf + (b * PRED + (s - HIST)) * 6; }
    float val = 0.f;
    if (tid < DIN) {
        int c = tid;
        if      (c < 64)  val = dayE[f[0] * 64 + c];
        else if (c < 128) val = timeE[f[1] * 64 + (c - 64)];
        else if (c < 192) val = dowE[f[3] * 64 + (c - 128)];
        else if (c < 224) val = wdE[f[4] * 32 + (c - 192)];
        else if (c == 224) val = (float)f[5];
        else val = (loc >= 0) ? locE[(size_t)loc * 256 + (c - 225)] : 0.f;
    }
    red[tid] = (tid < DIN) ? val : 0.f;
    __syncthreads();
    for (int o = 256; o > 0; o >>= 1) { if (tid < o) red[tid] += red[tid + o]; __syncthreads(); }
    float mean = red[0] / (float)DIN;
    __syncthreads();
    float d = (tid < DIN) ? (val - mean) : 0.f;
    red[tid] = d * d;
    __syncthreads();
    for (int o = 256; o > 0; o >>= 1) { if (tid < o) red[tid] += red[tid + o]; __syncthreads(); }
    float rstd = rsqrtf(red[0] / (float)DIN + 1e-5f);
    if (tid < DINP)
        xb[(size_t)tok * DINP + tid] =
            (tid < DIN) ? f2bf((val - mean) * rstd * g[tid] + b2[tid]) : (short)0;
}

// ================= LayerNorm(768), fused adds, dual f32+bf16 out ==========
__global__ __launch_bounds__(256)
void ln768(float* __restrict__ out, short* __restrict__ outb,
           const float* __restrict__ in1, const float* __restrict__ in2,
           const float* __restrict__ pos, const float* __restrict__ tt,
           const float* __restrict__ g, const float* __restrict__ b2,
           float eps)
{
    const int D = HH;
    const int row = blockIdx.x;
    const int s = row % SS;
    __shared__ float buf[HH];
    __shared__ float red[256];
    const int tid = threadIdx.x;
    float partial = 0.f;
    #pragma unroll
    for (int i = 0; i < 3; ++i) {
        int c = tid + i * 256;
        float v = in1[(size_t)row * D + c];
        if (in2) v += in2[(size_t)row * D + c];
        if (pos) v += pos[(size_t)s * D + c];
        if (tt)  v += tt[c];
        buf[c] = v;
        partial += v;
    }
    red[tid] = partial; __syncthreads();
    for (int o = 128; o > 0; o >>= 1) { if (tid < o) red[tid] += red[tid + o]; __syncthreads(); }
    float mean = red[0] / (float)D;
    __syncthreads();
    float p2 = 0.f;
    #pragma unroll
    for (int i = 0; i < 3; ++i) { float d = buf[tid + i * 256] - mean; p2 += d * d; }
    red[tid] = p2; __syncthreads();
    for (int o = 128; o > 0; o >>= 1) { if (tid < o) red[tid] += red[tid + o]; __syncthreads(); }
    float rstd = rsqrtf(red[0] / (float)D + eps);
    #pragma unroll
    for (int i = 0; i < 3; ++i) {
        int c = tid + i * 256;
        float v = (buf[c] - mean) * rstd * g[c] + b2[c];
        out[(size_t)row * D + c] = v;
        if (outb) outb[(size_t)row * D + c] = f2bf(v);
    }
}

// ================= gathers =================
__global__ void gather_fut_f32(const float* __restrict__ src, float* __restrict__ dst, int D)
{
    const int r = blockIdx.x;
    const int b = r / PRED, t = r % PRED;
    const int srow = b * SS + HIST + t;
    for (int c = threadIdx.x; c < D; c += blockDim.x)
        dst[(size_t)r * D + c] = src[(size_t)srow * D + c];
}
__global__ void gather_fut_b16(const short* __restrict__ src, short* __restrict__ dst, int D)
{
    const int r = blockIdx.x;
    const int b = r / PRED, t = r % PRED;
    const int srow = b * SS + HIST + t;
    for (int c = threadIdx.x; c < D; c += blockDim.x)
        dst[(size_t)r * D + c] = src[(size_t)srow * D + c];
}

// ================= gate =================
__global__ __launch_bounds__(256)
void gate_kernel(const float* __restrict__ Xf, const float* __restrict__ Wg,
                 const float* __restrict__ bg, float* __restrict__ out)
{
    const int row = blockIdx.x;
    const int tid = threadIdx.x;
    float a[NE_] = {};
    for (int k = tid; k < HH; k += 256) {
        float xv = Xf[(size_t)row * HH + k];
        #pragma unroll
        for (int e = 0; e < NE_; ++e) a[e] = fmaf(xv, Wg[k * NE_ + e], a[e]);
    }
    __shared__ float red[256];
    #pragma unroll
    for (int e = 0; e < NE_; ++e) {
        red[tid] = a[e]; __syncthreads();
        for (int o = 128; o > 0; o >>= 1) { if (tid < o) red[tid] += red[tid + o]; __syncthreads(); }
        if (tid == 0) out[(size_t)row * NE_ + e] = red[0] + bg[e];
        __syncthreads();
    }
}

__global__ void gate_softmax(float* __restrict__ gate)
{
    const int r = blockIdx.x * blockDim.x + threadIdx.x;
    if (r >= BB * PRED) return;
    float* p = gate + (size_t)r * NE_;
    float mx = p[0];
    for (int e = 1; e < NE_; ++e) mx = fmaxf(mx, p[e]);
    float s = 0.f, v[NE_];
    for (int e = 0; e < NE_; ++e) { v[e] = __expf(p[e] - mx); s += v[e]; }
    for (int e = 0; e < NE_; ++e) p[e] = v[e] / s;
}

// ============ MoE gated reduce: futm += sum_e g[e]*eo[row][e*768+c] ========
__global__ __launch_bounds__(256)
void moe_reduce(const float* __restrict__ eo, const float* __restrict__ gp,
                float* __restrict__ futm)
{
    const int row = blockIdx.x;
    float g[NE_];
    #pragma unroll
    for (int e = 0; e < NE_; ++e) g[e] = gp[row * NE_ + e];
    for (int c = threadIdx.x; c < HH; c += 256) {
        float s = futm[(size_t)row * HH + c];
        #pragma unroll
        for (int e = 0; e < NE_; ++e)
            s = fmaf(g[e], eo[(size_t)row * (NE_ * HH) + e * HH + c], s);
        futm[(size_t)row * HH + c] = s;
    }
}

// ================= host =================
extern "C" void kernel_launch(void* const* d_in, const int* in_sizes, int n_in,
                              void* d_out, int out_size, void* d_ws, size_t ws_size,
                              hipStream_t stream)
{
    const int*   isf   = (const int*)  d_in[0];
    const int*   hloc  = (const int*)  d_in[1];
    const int*   psf   = (const int*)  d_in[2];
    const float* dayE  = (const float*)d_in[3];
    const float* timeE = (const float*)d_in[4];
    const float* dowE  = (const float*)d_in[5];
    const float* wdE   = (const float*)d_in[6];
    const float* locE  = (const float*)d_in[7];
    const float* ln_g  = (const float*)d_in[8];
    const float* ln_b  = (const float*)d_in[9];
    const float* inpW  = (const float*)d_in[10];
    const float* inpB  = (const float*)d_in[11];
    const float* resW  = (const float*)d_in[12];
    const float* resB  = (const float*)d_in[13];
    const float* saqW  = (const float*)d_in[14];
    const float* sakW  = (const float*)d_in[15];
    const float* savW  = (const float*)d_in[16];
    const float* saoW  = (const float*)d_in[17];
    const float* saqB  = (const float*)d_in[18];
    const float* sakB  = (const float*)d_in[19];
    const float* savB  = (const float*)d_in[20];
    const float* saoB  = (const float*)d_in[21];
    const float* salnG = (const float*)d_in[22];
    const float* salnB = (const float*)d_in[23];
    const float* posE  = (const float*)d_in[24];
    const float* ttE   = (const float*)d_in[25];
    const float* belnG = (const float*)d_in[26];
    const float* belnB = (const float*)d_in[27];
    const float* bqW   = (const float*)d_in[28];
    const float* bkW   = (const float*)d_in[29];
    const float* bvW   = (const float*)d_in[30];
    const float* boW   = (const float*)d_in[31];
    const float* bqB   = (const float*)d_in[32];
    const float* bkB   = (const float*)d_in[33];
    const float* bvB   = (const float*)d_in[34];
    const float* boB   = (const float*)d_in[35];
    const float* balnG = (const float*)d_in[36];
    const float* balnB = (const float*)d_in[37];
    const float* bf1W  = (const float*)d_in[38];
    const float* bf1B  = (const float*)d_in[39];
    const float* bf2W  = (const float*)d_in[40];
    const float* bf2B  = (const float*)d_in[41];
    const float* bflnG = (const float*)d_in[42];
    const float* bflnB = (const float*)d_in[43];
    const float* moeW  = (const float*)d_in[44];
    const float* moeB  = (const float*)d_in[45];
    const float* gateW = (const float*)d_in[46];
    const float* gateB = (const float*)d_in[47];
    const float* outW  = (const float*)d_in[48];
    const float* outB  = (const float*)d_in[49];

    const int N6 = BB * SS;            // 6144
    const int NF = BB * PRED;          // 768

    char* base = (char*)d_ws;
    size_t off = 0;
    auto alloc = [&](size_t bytes) -> void* {
        void* p = base + off;
        off = (off + bytes + 255) & ~(size_t)255;
        return p;
    };

    short* xb     = (short*)alloc((size_t)N6 * DINP * 2);
    short* hb     = (short*)alloc((size_t)N6 * HH * 2);
    short* Ob     = (short*)alloc((size_t)N6 * HH * 2);
    // --- contiguous trio reused as overlay after encoder ---
    short* QKVb   = (short*)alloc((size_t)N6 * 3 * HH * 2);  // 28.3 MB
    float* Cb     = (float*)alloc((size_t)N6 * HH * 4);      // 18.9 MB
    short* ffb    = (short*)alloc((size_t)N6 * FF_ * 2);     // 37.7 MB
    // -------------------------------------------------------
    float* Hh     = (float*)alloc((size_t)N6 * HH * 4);
    float* Abuf   = (float*)alloc((size_t)N6 * HH * 4);
    short* inpWt  = (short*)alloc((size_t)HH * DINP * 2);
    short* resWt  = (short*)alloc((size_t)HH * DINP * 2);
    short* saWt   = (short*)alloc((size_t)3 * HH * HH * 2);
    short* saoWt  = (short*)alloc((size_t)HH * HH * 2);
    short* lqkvWt = (short*)alloc((size_t)3 * HH * HH * 2);
    short* loWt   = (short*)alloc((size_t)HH * HH * 2);
    short* lf1Wt  = (short*)alloc((size_t)FF_ * HH * 2);
    short* lf2Wt  = (short*)alloc((size_t)HH * FF_ * 2);
    float* futh   = (float*)alloc((size_t)NF * HH * 4);
    float* futm   = (float*)alloc((size_t)NF * HH * 4);
    float* futg   = (float*)alloc((size_t)NF * NE_ * 4);

    // overlay (post-encoder) inside QKVb..ffb (84.9 MB > 74.1 MB needed)
    short* outWt = QKVb;                              // [40064][768]
    short* moeWt = outWt + (size_t)VVP * HH;          // [6144][768]
    short* futhb = moeWt + (size_t)NE_ * HH * HH;
    short* futxb = futhb + (size_t)NF * HH;
    short* futmb = futxb + (size_t)NF * DINP;

    // ---- features + input LN -> bf16 x ----
    build_x<<<N6, 512, 0, stream>>>(isf, hloc, psf, dayE, timeE, dowE, wdE, locE,
                                    ln_g, ln_b, xb);

    // ---- upfront weight prep ----
    dim3 tb(32, 8);
    transpose_cvt_b<<<dim3(HH/32, DINP/32, 1), tb, 0, stream>>>(inpW, inpWt, DIN, HH, DINP, 0, 0);
    transpose_cvt_b<<<dim3(HH/32, DINP/32, 1), tb, 0, stream>>>(resW, resWt, DIN, HH, DINP, 0, 0);
    transpose_cvt_b<<<dim3(HH/32, HH/32, 1), tb, 0, stream>>>(saqW, saWt,                   HH, HH, HH, 0, 0);
    transpose_cvt_b<<<dim3(HH/32, HH/32, 1), tb, 0, stream>>>(sakW, saWt + (size_t)HH*HH,   HH, HH, HH, 0, 0);
    transpose_cvt_b<<<dim3(HH/32, HH/32, 1), tb, 0, stream>>>(savW, saWt + (size_t)2*HH*HH, HH, HH, HH, 0, 0);
    transpose_cvt_b<<<dim3(HH/32, HH/32, 1), tb, 0, stream>>>(saoW, saoWt, HH, HH, HH, 0, 0);

    // ---- proj = LN(x) @ inpW  (dual: Abuf f32 + hb bf16) ----
    gemm_bf16<6><<<dim3(HH/128, N6/128), 256, 0, stream>>>(
        xb, inpWt, inpB, nullptr, nullptr, Abuf, hb, DINP, HH, HH);

    // ---- SA block (16 heads, hd=48) ----
    gemm_bf16<5><<<dim3(3*HH/128, N6/128), 256, 0, stream>>>(
        hb, saWt, saqB, sakB, savB, QKVb, nullptr, HH, 3*HH, 3*HH);
    attn_mfma<48><<<BB*16*6, 256, 0, stream>>>(
        QKVb, QKVb + HH, QKVb + 2*HH, Ob, 16, 3*HH, HH, 1.f / sqrtf(48.f));
    gemm_bf16<0><<<dim3(HH/128, N6/128), 256, 0, stream>>>(
        Ob, saoWt, saoB, nullptr, nullptr, Cb, nullptr, HH, HH, HH);
    ln768<<<N6, 256, 0, stream>>>(Hh, nullptr, Cb, Abuf, nullptr, nullptr,
                                  salnG, salnB, 1e-5f);

    // ---- BERT embeddings LN (dual -> hb for first layer QKV) ----
    ln768<<<N6, 256, 0, stream>>>(Hh, hb, Hh, nullptr, posE, ttE,
                                  belnG, belnB, 1e-12f);

    // ---- 12 encoder layers ----
    for (int i = 0; i < NL; ++i) {
        const size_t wo = (size_t)i * HH * HH;
        const size_t bo = (size_t)i * HH;
        prep_layer_w<<<6912, 256, 0, stream>>>(
            bqW + wo, bkW + wo, bvW + wo, boW + wo,
            bf1W + (size_t)i * HH * FF_, bf2W + (size_t)i * FF_ * HH,
            lqkvWt, loWt, lf1Wt, lf2Wt);

        gemm_bf16<5><<<dim3(3*HH/128, N6/128), 256, 0, stream>>>(
            hb, lqkvWt, bqB + bo, bkB + bo, bvB + bo, QKVb, nullptr, HH, 3*HH, 3*HH);
        attn_mfma<64><<<BB*12*6, 256, 0, stream>>>(
            QKVb, QKVb + HH, QKVb + 2*HH, Ob, 12, 3*HH, HH, 0.125f);
        gemm_bf16<0><<<dim3(HH/128, N6/128), 256, 0, stream>>>(
            Ob, loWt, boB + bo, nullptr, nullptr, Cb, nullptr, HH, HH, HH);
        ln768<<<N6, 256, 0, stream>>>(Abuf, hb, Cb, Hh, nullptr, nullptr,
                                      balnG + bo, balnB + bo, 1e-12f);
        gemm_bf16<4><<<dim3(FF_/128, N6/128), 256, 0, stream>>>(
            hb, lf1Wt, bf1B + (size_t)i * FF_, nullptr, nullptr, ffb, nullptr, HH, FF_, FF_);
        gemm_bf16<0><<<dim3(HH/128, N6/128), 256, 0, stream>>>(
            ffb, lf2Wt, bf2B + bo, nullptr, nullptr, Cb, nullptr, FF_, HH, HH);
        ln768<<<N6, 256, 0, stream>>>(Hh, hb, Cb, Abuf, nullptr, nullptr,
                                      bflnG + bo, bflnB + bo, 1e-12f);
    }

    // ---- future slice (f32 for gate, bf16 for MoE/res GEMMs) ----
    gather_fut_f32<<<NF, 256, 0, stream>>>(Hh, futh, HH);
    gather_fut_b16<<<NF, 256, 0, stream>>>(hb, futhb, HH);
    gather_fut_b16<<<NF, 256, 0, stream>>>(xb, futxb, DINP);

    // ---- residual path ----
    gemm_bf16<0><<<dim3(HH/128, NF/128), 256, 0, stream>>>(
        futxb, resWt, resB, nullptr, nullptr, futm, nullptr, DINP, HH, HH);

    // ---- gate ----
    gate_kernel<<<NF, 256, 0, stream>>>(futh, gateW, gateB, futg);
    gate_softmax<<<3, 256, 0, stream>>>(futg);

    // ---- MoE: 8 experts fused (eo -> Hh region, dead now) ----
    transpose_cvt_b<<<dim3(HH/32, HH/32, NE_), tb, 0, stream>>>(
        moeW, moeWt, HH, HH, HH, (size_t)HH*HH, (size_t)HH*HH);
    gemm_bf16<1><<<dim3(NE_*HH/128, NF/128), 256, 0, stream>>>(
        futhb, moeWt, moeB, nullptr, nullptr, Hh, nullptr, HH, NE_*HH, NE_*HH);
    moe_reduce<<<NF, 256, 0, stream>>>(Hh, futg, futm);

    // ---- head: logits for future tokens ----
    {
        int n4 = (int)((size_t)NF * HH / 4);
        cvt_bf16<<<(n4 + 255) / 256, 256, 0, stream>>>(futm, futmb, n4);
    }
    transpose_cvt_b<<<dim3(VVP/32, HH/32, 1), tb, 0, stream>>>(
        outW, outWt, HH, VV, HH, 0, 0);
    gemm_bf16<0><<<dim3(VVP/128, NF/128), 256, 0, stream>>>(
        futmb, outWt, outB, nullptr, nullptr, (float*)d_out, nullptr, HH, VV, VV);
}